// Round 17
// baseline (206.640 us; speedup 1.0000x reference)
//
#include <hip/hip_runtime.h>
#include <hip/hip_bf16.h>
#include <hip/hip_fp16.h>
#include <hip/hip_fp8.h>

// DeformableAttention on MI355X.
// prep_all(weights^T bf16 + global fp8 rpe quad table) -> gemm_bf16(q) ->
// fused conv+LN+GELU+pos+sample (branch-free taps) -> gemm_bf16(kv; K->kvb,
// V->vtb transposed epilogue) -> fused flash-attn v14 (UNSWAPPED body,
// V^T + pos direct from global, ZERO barriers in the kt loop, wave-local P)
// -> gemm_bf16(out,+bias)

#define EPS_ 1e-5f
#define ASCALE 0.17677669529663687f      // 1/sqrt(32)
#define LOG2E  1.4426950408889634f

typedef __attribute__((ext_vector_type(8))) short bf16x8;
typedef __attribute__((ext_vector_type(4))) float f32x4;

__device__ __forceinline__ short f2bf(float f) {
  union { float f; unsigned u; } v; v.f = f;
  unsigned r = (v.u + 0x7fffu + ((v.u >> 16) & 1u)) >> 16;  // RNE
  return (short)r;
}
__device__ __forceinline__ unsigned pk2bf(float a, float b) {
  union { __hip_bfloat162 h; unsigned u; } v;
  v.h = __float22bfloat162_rn(make_float2(a, b));
  return v.u;
}
__device__ __forceinline__ float exp2_fast(float x) {
  return __builtin_amdgcn_exp2f(x);
}

// fp8 e4m3 quad pack/unpack: HW v_cvt_pk_* on gfx950, sw fallback otherwise.
__device__ __forceinline__ unsigned pack_fp8_quad(float v00, float v10,
                                                  float v01, float v11) {
#if __has_builtin(__builtin_amdgcn_cvt_pk_fp8_f32)
  int r = 0;
  r = __builtin_amdgcn_cvt_pk_fp8_f32(v00, v10, r, false);  // bytes 0,1
  r = __builtin_amdgcn_cvt_pk_fp8_f32(v01, v11, r, true);   // bytes 2,3
  return (unsigned)r;
#else
  __hip_fp8x2_e4m3 elo(make_float2(v00, v10));
  __hip_fp8x2_e4m3 ehi(make_float2(v01, v11));
  return (unsigned)(unsigned short)elo.__x |
         ((unsigned)(unsigned short)ehi.__x << 16);
#endif
}
__device__ __forceinline__ void unpack_fp8_quad(unsigned u, float& g00,
                                                float& g10, float& g01,
                                                float& g11) {
#if __has_builtin(__builtin_amdgcn_cvt_pk_f32_fp8)
  auto ga = __builtin_amdgcn_cvt_pk_f32_fp8((int)u, false);  // (v00, v10)
  auto gb = __builtin_amdgcn_cvt_pk_f32_fp8((int)u, true);   // (v01, v11)
  g00 = ga[0]; g10 = ga[1]; g01 = gb[0]; g11 = gb[1];
#else
  __hip_fp8x2_e4m3 plo, phi;
  plo.__x = (__hip_fp8x2_storage_t)(unsigned short)(u & 0xffffu);
  phi.__x = (__hip_fp8x2_storage_t)(unsigned short)(u >> 16);
  float2 fa = (float2)plo, fb = (float2)phi;
  g00 = fa.x; g10 = fa.y; g01 = fb.x; g11 = fb.y;
#endif
}

// ---------------------------------------------------------------------------
// Prep: bids [0,1024) weight transposes; bids [1024,1152) build the global
// fp8 rpe quad table (8 x 64 x 64 u32), once per head.
// ---------------------------------------------------------------------------
__global__ __launch_bounds__(256) void prep_all(
    const float* __restrict__ Wkv, const float* __restrict__ Wout,
    const float* __restrict__ Wq, const float* __restrict__ rpe,
    short* __restrict__ Wkvt, short* __restrict__ Woutt,
    short* __restrict__ Wqt, unsigned* __restrict__ rpeq)
{
  int bid = blockIdx.x, k = threadIdx.x;
  if (bid >= 1024) {
    int i = (bid - 1024) * 256 + k;   // 0..32767
    int h = i >> 12, idx = i & 4095;
    int ty = idx >> 6, tx = idx & 63;
    const float* rp = rpe + h * 3969;
    float v00 = 0.f, v10 = 0.f, v01 = 0.f, v11 = 0.f;
    if (tx <= 62) {
      if (ty <= 62) v00 = rp[ty * 63 + tx] * LOG2E;
      if (ty <= 61) v10 = rp[(ty + 1) * 63 + tx] * LOG2E;
    }
    if (tx <= 61) {
      if (ty <= 62) v01 = rp[ty * 63 + tx + 1] * LOG2E;
      if (ty <= 61) v11 = rp[(ty + 1) * 63 + tx + 1] * LOG2E;
    }
    rpeq[i] = pack_fp8_quad(v00, v10, v01, v11);
    return;
  }
  if (bid < 512) Wkvt[bid * 256 + k] = f2bf(Wkv[k * 512 + bid]);
  else if (bid < 768) { int n = bid - 512; Woutt[n * 256 + k] = f2bf(Wout[k * 256 + n]); }
  else { int n = bid - 768; Wqt[n * 256 + k] = f2bf(Wq[k * 256 + n]); }
}

// ---------------------------------------------------------------------------
// bf16 MFMA GEMM: C[M,N] = A[M,256] @ Bt[N,256]^T (+bias), with prefetch.
// If vt != null: blocks with n0 >= 256 write V^T to vt[b][d][j] (bf16)
// via an LDS transpose (coalesced b128 stores) and skip the normal C write
// (kvb's V-half is unused by attn v14).
// ---------------------------------------------------------------------------
__global__ __launch_bounds__(256) void gemm_bf16(
    const short* __restrict__ Ab, const float* __restrict__ Af,
    const short* __restrict__ Bt,
    float* __restrict__ Cf, short* __restrict__ Cb,
    const float* __restrict__ bias, int N, short* __restrict__ vt)
{
  __shared__ __align__(16) short smem[5120];   // As(2560) | Bs(2560); reused as sV[64][72]
  short* As = smem;
  short* Bs = smem + 2560;
  const int t = threadIdx.x;
  const int n0 = blockIdx.x << 6, m0 = blockIdx.y << 6;
  const int wv = t >> 6, l16 = t & 15, quad = (t & 63) >> 4;
  const int row = t >> 2, koff = (t & 3) << 3;

  auto loadA = [&](int k0) -> bf16x8 {
    if (Af) {
      const float* src = &Af[(size_t)(m0 + row) * 256 + k0 + koff];
      float4 f0 = *(const float4*)src;
      float4 f1 = *(const float4*)(src + 4);
      union { unsigned u[4]; bf16x8 v; } c;
      c.u[0] = pk2bf(f0.x, f0.y); c.u[1] = pk2bf(f0.z, f0.w);
      c.u[2] = pk2bf(f1.x, f1.y); c.u[3] = pk2bf(f1.z, f1.w);
      return c.v;
    }
    return *(const bf16x8*)&Ab[(size_t)(m0 + row) * 256 + k0 + koff];
  };

  f32x4 acc[4] = {};
  bf16x8 av = loadA(0);
  bf16x8 bv = *(const bf16x8*)&Bt[(size_t)(n0 + row) * 256 + koff];
  for (int k0 = 0; k0 < 256; k0 += 32) {
    __syncthreads();  // prior-iter frag reads done before overwrite
    *(bf16x8*)&As[row * 40 + koff] = av;
    *(bf16x8*)&Bs[row * 40 + koff] = bv;
    __syncthreads();
    if (k0 + 32 < 256) {  // prefetch next chunk before MFMA section
      av = loadA(k0 + 32);
      bv = *(const bf16x8*)&Bt[(size_t)(n0 + row) * 256 + k0 + 32 + koff];
    }
    bf16x8 a = *(const bf16x8*)&As[((wv << 4) + l16) * 40 + (quad << 3)];
#pragma unroll
    for (int jt = 0; jt < 4; jt++) {
      bf16x8 bb = *(const bf16x8*)&Bs[((jt << 4) + l16) * 40 + (quad << 3)];
      acc[jt] = __builtin_amdgcn_mfma_f32_16x16x32_bf16(a, bb, acc[jt], 0, 0, 0);
    }
  }

  if (vt && n0 >= 256) {
    // ---- V^T epilogue (v4-proven): stage C-tile into LDS as [d][j].
    __syncthreads();                     // done with As/Bs MFMA reads
    short* sV = smem;                    // [64][72] shorts (9216 B <= 10240)
#pragma unroll
    for (int jt = 0; jt < 4; jt++) {
#pragma unroll
      for (int r = 0; r < 4; r++) {
        int nl = (jt << 4) + l16;                 // d-local
        int ml = (wv << 4) + (quad << 2) + r;     // j-local
        sV[nl * 72 + ml] = f2bf(acc[jt][r]);
      }
    }
    __syncthreads();
    int dl = t >> 2, js0 = (t & 3) << 3;
    bf16x8 v0 = *(const bf16x8*)&sV[dl * 72 + js0];
    bf16x8 v1 = *(const bf16x8*)&sV[dl * 72 + js0 + 32];
    int bb = m0 >> 10, j0 = m0 & 1023;
    size_t base = ((size_t)((bb << 8) + (n0 - 256) + dl) << 10) + j0;
    *(bf16x8*)&vt[base + js0]      = v0;
    *(bf16x8*)&vt[base + js0 + 32] = v1;
    return;
  }

#pragma unroll
  for (int jt = 0; jt < 4; jt++) {
#pragma unroll
    for (int r = 0; r < 4; r++) {
      int mrow = m0 + (wv << 4) + (quad << 2) + r;
      int ncol = n0 + (jt << 4) + l16;
      float v = acc[jt][r];
      if (bias) v += bias[ncol];
      if (Cf) Cf[(size_t)mrow * N + ncol] = v;
      else    Cb[(size_t)mrow * N + ncol] = f2bf(v);
    }
  }
}

// ---------------------------------------------------------------------------
// Fused: conv5x5 depthwise + LN(128) + GELU + @Woff + tanh -> pos, then
// grid_sample of this pixel's group channels -> xs (bf16). Wave per (b,g,pix).
// Branch-free taps (clamp + weight*mask); weights preloaded to registers.
// ---------------------------------------------------------------------------
__global__ __launch_bounds__(256) void conv_pos_sample_kernel(
    const float* __restrict__ q, const float* __restrict__ conv_w,
    const float* __restrict__ conv_b, const float* __restrict__ ln_g,
    const float* __restrict__ ln_b, const float* __restrict__ Woff,
    float* __restrict__ pos, short* __restrict__ xsb)
{
  const int p = (blockIdx.x << 2) + (threadIdx.x >> 6);
  const int lane = threadIdx.x & 63;
  const int bg = p >> 10, pix = p & 1023;
  const int hh = pix >> 5, ww = pix & 31;
  const int b = bg >> 1, g = bg & 1;
  const int c0 = lane << 1;
  const float* qbase = q + ((size_t)(b << 10) << 8) + (g << 7) + c0;

  float wr0[25], wr1[25];
  {
    const float* w0 = conv_w + c0 * 25;
#pragma unroll
    for (int i = 0; i < 25; i++) { wr0[i] = w0[i]; wr1[i] = w0[i + 25]; }
  }

  float2 cb = *(const float2*)&conv_b[c0];
  float a0 = cb.x, a1 = cb.y;
#pragma unroll
  for (int dy = 0; dy < 5; dy++) {
    int y = hh + dy - 2;
    int yc = y < 0 ? 0 : (y > 31 ? 31 : y);
    float my = ((unsigned)y < 32u) ? 1.f : 0.f;
#pragma unroll
    for (int dx = 0; dx < 5; dx++) {
      int x = ww + dx - 2;
      int xc = x < 0 ? 0 : (x > 31 ? 31 : x);
      float m = ((unsigned)x < 32u) ? my : 0.f;
      float2 qv = *(const float2*)&qbase[(size_t)((yc << 5) + xc) << 8];
      a0 = fmaf(qv.x * m, wr0[dy * 5 + dx], a0);
      a1 = fmaf(qv.y * m, wr1[dy * 5 + dx], a1);
    }
  }
  float s1 = a0 + a1, s2 = a0 * a0 + a1 * a1;
#pragma unroll
  for (int o = 32; o; o >>= 1) { s1 += __shfl_xor(s1, o); s2 += __shfl_xor(s2, o); }
  float mu = s1 * (1.f / 128.f);
  float inv = rsqrtf(fmaf(-mu, mu, s2 * (1.f / 128.f)) + EPS_);
  float2 lg = *(const float2*)&ln_g[c0];
  float2 lb = *(const float2*)&ln_b[c0];
  float v0 = (a0 - mu) * inv * lg.x + lb.x;
  float v1 = (a1 - mu) * inv * lg.y + lb.y;
  float ge0 = 0.5f * v0 * (1.f + erff(v0 * 0.70710678118654752f));
  float ge1 = 0.5f * v1 * (1.f + erff(v1 * 0.70710678118654752f));
  float2 W0 = *(const float2*)&Woff[c0 * 2];
  float2 W1 = *(const float2*)&Woff[c0 * 2 + 2];
  float o0 = ge0 * W0.x + ge1 * W1.x;
  float o1 = ge0 * W0.y + ge1 * W1.y;
#pragma unroll
  for (int o = 32; o; o >>= 1) { o0 += __shfl_xor(o0, o); o1 += __shfl_xor(o1, o); }
  float py = tanhf(o0) * 0.0625f + ((hh + 0.5f) * 0.0625f - 1.f);
  float px = tanhf(o1) * 0.0625f + ((ww + 0.5f) * 0.0625f - 1.f);
  if (lane == 0)
    ((float2*)pos)[(bg << 10) + pix] = make_float2(py, px);

  float x = (px + 1.f) * 15.5f;
  float y = (py + 1.f) * 15.5f;
  float x0f = floorf(x), y0f = floorf(y);
  int ix0 = (int)x0f, iy0 = (int)y0f;
  float fx = x - x0f, fy = y - y0f;
  float ac0 = 0.f, ac1 = 0.f;
#pragma unroll
  for (int dy = 0; dy < 2; dy++) {
#pragma unroll
    for (int dx = 0; dx < 2; dx++) {
      int yi = iy0 + dy, xi = ix0 + dx;
      int yc = yi < 0 ? 0 : (yi > 31 ? 31 : yi);
      int xc = xi < 0 ? 0 : (xi > 31 ? 31 : xi);
      float valid = ((unsigned)yi < 32u && (unsigned)xi < 32u) ? 1.f : 0.f;
      float w = (dy ? fy : 1.f - fy) * (dx ? fx : 1.f - fx) * valid;
      float2 qv = *(const float2*)&qbase[(size_t)((yc << 5) + xc) << 8];
      ac0 = fmaf(w, qv.x, ac0);
      ac1 = fmaf(w, qv.y, ac1);
    }
  }
  *(unsigned*)&xsb[(size_t)((b << 10) + pix) * 256 + (g << 7) + c0] = pk2bf(ac0, ac1);
}

// ---------------------------------------------------------------------------
// Fused attention v14: unswapped body (v12 math), V^T B-frags and pos read
// DIRECT from global (vtb L2-hot, v5-proven access pattern), wave-local P.
// ZERO barriers in the kt loop (one after the rpe8 copy).  Removes 128
// scalar ds_writes + 32 barrier drains per block vs v13c.
// One block = (64-row i-tile, head, batch), grid 1024, 34 KB LDS ->
// 4 blocks/CU.  Fixed-m softmax in exp2 domain; l via ones-MFMA.
// ---------------------------------------------------------------------------
__global__ __launch_bounds__(256, 4) void attn_kernel(
    const float* __restrict__ q, const short* __restrict__ kvb,
    const short* __restrict__ vtb, const float* __restrict__ pos,
    const unsigned* __restrict__ rpeq, short* __restrict__ ao)
{
  const int it = blockIdx.x, h = blockIdx.y, b = blockIdx.z;
  const int g = h >> 2, t = threadIdx.x;
  const int wv = t >> 6, l16 = t & 15, quad = (t & 63) >> 4;

  __shared__ __align__(16) short PL[64 * 72];       // 9 KB P (wave-local rows)
  __shared__ __align__(16) unsigned rpe8[64 * 64];  // 16 KB fp8 quad table

  // ---- stage fp8 rpe quad table: coalesced copy from prebuilt rpeq
  {
    const unsigned* src = rpeq + (h << 12);
    for (int i = t; i < 4096; i += 256) rpe8[i] = src[i];
  }

  // ---- Q A-frag from global (once), scaled by ASCALE*LOG2E
  const int row0 = (it << 6) + (wv << 4);
  bf16x8 aq;
  {
    const float* src = q + (size_t)((b << 10) + row0 + l16) * 256 + (h << 5) + (quad << 3);
    float4 f0 = *(const float4*)src;
    float4 f1 = *(const float4*)(src + 4);
    const float sc = ASCALE * LOG2E;
    union { unsigned u[4]; bf16x8 v; } c;
    c.u[0] = pk2bf(f0.x * sc, f0.y * sc); c.u[1] = pk2bf(f0.z * sc, f0.w * sc);
    c.u[2] = pk2bf(f1.x * sc, f1.y * sc); c.u[3] = pk2bf(f1.z * sc, f1.w * sc);
    aq = c.v;
  }

  // sampling coords (origin +31): wave's 16 rows share one raster row
  const float ayc = 15.5f * (((row0 >> 5) + 0.5f) * 0.0625f - 1.f) + 31.f;
  float ax[4];
#pragma unroll
  for (int r = 0; r < 4; r++) {
    int ix = (row0 & 31) + (quad << 2) + r;
    ax[r] = 15.5f * ((ix + 0.5f) * 0.0625f - 1.f) + 31.f;
  }

  bf16x8 vones;
#pragma unroll
  for (int i = 0; i < 8; i++) vones[i] = (short)0x3F80;  // bf16 1.0

  // ---- strength-reduced pointer bases (advance by constants per kt)
  const short* ksrc = kvb + (size_t)((b << 10) + l16) * 512 + (h << 5) + (quad << 3);
  const short* vsrc = vtb + (((size_t)((b << 8) + (h << 5) + l16)) << 10) + (quad << 3);
  const float2* psrc = (const float2*)pos + (((b << 1) + g) << 10) + l16;

  f32x4 Oacc[2] = {};
  f32x4 lacc = {};

  __syncthreads();   // rpe8 table ready — the ONLY block-wide barrier

  for (int kt = 0; kt < 16; kt++) {
    // ---- QK^T: 4 K B-frags from global (L1/L2) + 4 MFMA
    f32x4 S[4];
#pragma unroll
    for (int jt = 0; jt < 4; jt++) {
      bf16x8 bk = *(const bf16x8*)(ksrc + (size_t)jt * 8192);
      f32x4 z = {};
      S[jt] = __builtin_amdgcn_mfma_f32_16x16x32_bf16(aq, bk, z, 0, 0, 0);
    }

    // ---- per-jt: pos direct from global (broadcast across quads), y-chain,
    //      bias sample + p = exp2(S+bias)   (v12-exact math)
    unsigned pu[4][2];
#pragma unroll
    for (int jt = 0; jt < 4; jt++) {
      float2 pp = psrc[jt << 4];
      float ys = fmaf(-15.5f, pp.x, ayc);
      float y0f = floorf(ys);
      float fy = ys - y0f;
      int ybase = (int)y0f << 6;
      float wy = -15.5f * pp.y;
      float pv[4];
#pragma unroll
      for (int r = 0; r < 4; r++) {
        float sx = ax[r] + wy;
        float x0f = floorf(sx);
        float fx = sx - x0f;
        unsigned u = rpe8[ybase + (int)x0f];
        float g00, g10, g01, g11;
        unpack_fp8_quad(u, g00, g10, g01, g11);
        float h0 = fmaf(fx, g01 - g00, g00);
        float h1 = fmaf(fx, g11 - g10, g10);
        float bias = fmaf(fy, h1 - h0, h0);
        pv[r] = exp2_fast(S[jt][r] + bias);
      }
      pu[jt][0] = pk2bf(pv[0], pv[1]);
      pu[jt][1] = pk2bf(pv[2], pv[3]);
    }

    // ---- wave-local P write -> A-frag read (no barrier; same-wave order)
#pragma unroll
    for (int jt = 0; jt < 4; jt++) {
      int cb = (jt << 4) + l16;
      int rb = ((wv << 4) + (quad << 2)) * 72 + cb;
      PL[rb]       = (short)(pu[jt][0] & 0xffff);
      PL[rb + 72]  = (short)(pu[jt][0] >> 16);
      PL[rb + 144] = (short)(pu[jt][1] & 0xffff);
      PL[rb + 216] = (short)(pu[jt][1] >> 16);
    }
    bf16x8 pa0 = *(const bf16x8*)&PL[((wv << 4) + l16) * 72 + (quad << 3)];
    bf16x8 pa1 = *(const bf16x8*)&PL[((wv << 4) + l16) * 72 + 32 + (quad << 3)];

    // ---- PV: V^T B-frags direct from global vtb[b][d][j] (v5-proven)
#pragma unroll
    for (int dt = 0; dt < 2; dt++) {
      const short* vb = vsrc + ((size_t)dt << 14);   // d += 16 -> +16*1024
      bf16x8 vb0 = *(const bf16x8*)vb;               // j-half 0
      bf16x8 vb1 = *(const bf16x8*)(vb + 32);        // j-half 1
      Oacc[dt] = __builtin_amdgcn_mfma_f32_16x16x32_bf16(pa0, vb0, Oacc[dt], 0, 0, 0);
      Oacc[dt] = __builtin_amdgcn_mfma_f32_16x16x32_bf16(pa1, vb1, Oacc[dt], 0, 0, 0);
    }
    lacc = __builtin_amdgcn_mfma_f32_16x16x32_bf16(pa0, vones, lacc, 0, 0, 0);
    lacc = __builtin_amdgcn_mfma_f32_16x16x32_bf16(pa1, vones, lacc, 0, 0, 0);

    // ---- advance all bases to the next 64-j tile
    ksrc += 32768;   // 64 rows * 512 shorts
    vsrc += 64;      // j dimension
    psrc += 64;      // 64 float2
  }

  // ---- epilogue -> ao bf16
#pragma unroll
  for (int r = 0; r < 4; r++) {
    float inv = 1.f / lacc[r];
    int row = row0 + (quad << 2) + r;
#pragma unroll
    for (int dt = 0; dt < 2; dt++) {
      ao[(size_t)((b << 10) + row) * 256 + (h << 5) + (dt << 4) + l16] =
          f2bf(Oacc[dt][r] * inv);
    }
  }
}

// ---------------------------------------------------------------------------
extern "C" void kernel_launch(void* const* d_in, const int* in_sizes, int n_in,
                              void* d_out, int out_size, void* d_ws, size_t ws_size,
                              hipStream_t stream) {
  (void)in_sizes; (void)n_in; (void)out_size; (void)ws_size;
  const float* x      = (const float*)d_in[0];
  const float* Wq     = (const float*)d_in[1];
  const float* Wkv    = (const float*)d_in[2];
  const float* conv_w = (const float*)d_in[3];
  const float* conv_b = (const float*)d_in[4];
  const float* ln_g   = (const float*)d_in[5];
  const float* ln_b   = (const float*)d_in[6];
  const float* Woff   = (const float*)d_in[7];
  const float* rpe    = (const float*)d_in[8];
  const float* Wout   = (const float*)d_in[9];
  const float* bout   = (const float*)d_in[10];
  float* out = (float*)d_out;

  float* ws      = (float*)d_ws;
  float* q       = ws;                        // [0 .. 2097152)
  float* pos     = ws + 2097152;              // [.. 2129920)
  short* kvb     = (short*)(ws + 2129920);    // 8192*512 bf16 = 2,097,152 f32 [.. 4227072)
  short* xsb     = (short*)(ws + 4227072);    // 8192*256 bf16 = 1,048,576 f32 [.. 5275648)
  short* aob     = (short*)(ws + 5275648);    // 8192*256 bf16 = 1,048,576 f32 [.. 6324224)
  short* Wkvt    = (short*)(ws + 6324224);    // 512*256 bf16  =    65,536 f32 [.. 6389760)
  short* Woutt   = (short*)(ws + 6389760);    // 256*256 bf16  =    32,768 f32 [.. 6422528)
  short* Wqt     = (short*)(ws + 6422528);    // 256*256 bf16  =    32,768 f32 [.. 6455296)
  unsigned* rpeq = (unsigned*)(ws + 6455296); // 8*4096 u32    =    32,768 f32 [.. 6488064)
  short* vtb     = (short*)(ws + 6488064);    // 8*256*1024 bf16 = 1,048,576 f32 [.. 7536640)
  // total 7,536,640 f32 = 30.1 MB (v7 proved >= 30.3 MB available)

  // 0. weight transposes + global fp8 rpe quad table (merged)
  prep_all<<<1152, 256, 0, stream>>>(Wkv, Wout, Wq, rpe, Wkvt, Woutt, Wqt, rpeq);
  // 1. q = x @ Wq (bf16 MFMA, f32 A staged+converted, f32 out)
  gemm_bf16<<<dim3(4, 128), 256, 0, stream>>>(nullptr, x, Wqt, q, nullptr, nullptr, 256, nullptr);
  // 2+3. conv + LN + GELU + Woff + tanh -> pos, fused grid_sample -> xs
  conv_pos_sample_kernel<<<4096, 256, 0, stream>>>(q, conv_w, conv_b, ln_g, ln_b,
                                                   Woff, pos, xsb);
  // 4. kv = xs @ Wkv: K -> kvb (interleaved K-half), V -> vtb (transposed)
  gemm_bf16<<<dim3(8, 128), 256, 0, stream>>>(xsb, nullptr, Wkvt, nullptr, kvb, nullptr, 512, vtb);
  // 5. fused attention v14 (V/pos direct from global, zero kt barriers) -> ao
  attn_kernel<<<dim3(16, 8, 8), 256, 0, stream>>>(q, kvb, vtb, pos, rpeq, aob);
  // 6. out = ao @ Wout + bout (bf16 MFMA, f32 out)
  gemm_bf16<<<dim3(4, 128), 256, 0, stream>>>(aob, nullptr, Woutt, out, nullptr, bout, 256, nullptr);
}

// Round 18
// 190.425 us; speedup vs baseline: 1.0852x; 1.0852x over previous
//
#include <hip/hip_runtime.h>
#include <hip/hip_bf16.h>
#include <hip/hip_fp16.h>
#include <hip/hip_fp8.h>

// DeformableAttention on MI355X.
// prep_all(weights^T bf16 + global fp8 rpe quad table) -> gemm_bf16(q) ->
// fused conv+LN+GELU+pos+sample (branch-free taps) -> gemm_bf16(kv) ->
// fused flash-attn v15 (v13c body + pinned K prefetch + XCD-aware block
// swizzle: all 16 it-blocks of one (h,b) on one XCD -> K/V L2-resident)
// -> gemm_bf16(out,+bias)

#define EPS_ 1e-5f
#define ASCALE 0.17677669529663687f      // 1/sqrt(32)
#define LOG2E  1.4426950408889634f

typedef __attribute__((ext_vector_type(8))) short bf16x8;
typedef __attribute__((ext_vector_type(4))) float f32x4;

__device__ __forceinline__ short f2bf(float f) {
  union { float f; unsigned u; } v; v.f = f;
  unsigned r = (v.u + 0x7fffu + ((v.u >> 16) & 1u)) >> 16;  // RNE
  return (short)r;
}
__device__ __forceinline__ unsigned pk2bf(float a, float b) {
  union { __hip_bfloat162 h; unsigned u; } v;
  v.h = __float22bfloat162_rn(make_float2(a, b));
  return v.u;
}
__device__ __forceinline__ float exp2_fast(float x) {
  return __builtin_amdgcn_exp2f(x);
}

// fp8 e4m3 quad pack/unpack: HW v_cvt_pk_* on gfx950, sw fallback otherwise.
__device__ __forceinline__ unsigned pack_fp8_quad(float v00, float v10,
                                                  float v01, float v11) {
#if __has_builtin(__builtin_amdgcn_cvt_pk_fp8_f32)
  int r = 0;
  r = __builtin_amdgcn_cvt_pk_fp8_f32(v00, v10, r, false);  // bytes 0,1
  r = __builtin_amdgcn_cvt_pk_fp8_f32(v01, v11, r, true);   // bytes 2,3
  return (unsigned)r;
#else
  __hip_fp8x2_e4m3 elo(make_float2(v00, v10));
  __hip_fp8x2_e4m3 ehi(make_float2(v01, v11));
  return (unsigned)(unsigned short)elo.__x |
         ((unsigned)(unsigned short)ehi.__x << 16);
#endif
}
__device__ __forceinline__ void unpack_fp8_quad(unsigned u, float& g00,
                                                float& g10, float& g01,
                                                float& g11) {
#if __has_builtin(__builtin_amdgcn_cvt_pk_f32_fp8)
  auto ga = __builtin_amdgcn_cvt_pk_f32_fp8((int)u, false);  // (v00, v10)
  auto gb = __builtin_amdgcn_cvt_pk_f32_fp8((int)u, true);   // (v01, v11)
  g00 = ga[0]; g10 = ga[1]; g01 = gb[0]; g11 = gb[1];
#else
  __hip_fp8x2_e4m3 plo, phi;
  plo.__x = (__hip_fp8x2_storage_t)(unsigned short)(u & 0xffffu);
  phi.__x = (__hip_fp8x2_storage_t)(unsigned short)(u >> 16);
  float2 fa = (float2)plo, fb = (float2)phi;
  g00 = fa.x; g10 = fa.y; g01 = fb.x; g11 = fb.y;
#endif
}

// ---------------------------------------------------------------------------
// Prep: bids [0,1024) weight transposes; bids [1024,1152) build the global
// fp8 rpe quad table (8 x 64 x 64 u32), once per head.
// ---------------------------------------------------------------------------
__global__ __launch_bounds__(256) void prep_all(
    const float* __restrict__ Wkv, const float* __restrict__ Wout,
    const float* __restrict__ Wq, const float* __restrict__ rpe,
    short* __restrict__ Wkvt, short* __restrict__ Woutt,
    short* __restrict__ Wqt, unsigned* __restrict__ rpeq)
{
  int bid = blockIdx.x, k = threadIdx.x;
  if (bid >= 1024) {
    int i = (bid - 1024) * 256 + k;   // 0..32767
    int h = i >> 12, idx = i & 4095;
    int ty = idx >> 6, tx = idx & 63;
    const float* rp = rpe + h * 3969;
    float v00 = 0.f, v10 = 0.f, v01 = 0.f, v11 = 0.f;
    if (tx <= 62) {
      if (ty <= 62) v00 = rp[ty * 63 + tx] * LOG2E;
      if (ty <= 61) v10 = rp[(ty + 1) * 63 + tx] * LOG2E;
    }
    if (tx <= 61) {
      if (ty <= 62) v01 = rp[ty * 63 + tx + 1] * LOG2E;
      if (ty <= 61) v11 = rp[(ty + 1) * 63 + tx + 1] * LOG2E;
    }
    rpeq[i] = pack_fp8_quad(v00, v10, v01, v11);
    return;
  }
  if (bid < 512) Wkvt[bid * 256 + k] = f2bf(Wkv[k * 512 + bid]);
  else if (bid < 768) { int n = bid - 512; Woutt[n * 256 + k] = f2bf(Wout[k * 256 + n]); }
  else { int n = bid - 768; Wqt[n * 256 + k] = f2bf(Wq[k * 256 + n]); }
}

// ---------------------------------------------------------------------------
// bf16 MFMA GEMM: C[M,N] = A[M,256] @ Bt[N,256]^T (+bias), with prefetch.
// ---------------------------------------------------------------------------
__global__ __launch_bounds__(256) void gemm_bf16(
    const short* __restrict__ Ab, const float* __restrict__ Af,
    const short* __restrict__ Bt,
    float* __restrict__ Cf, short* __restrict__ Cb,
    const float* __restrict__ bias, int N)
{
  __shared__ __align__(16) short As[64 * 40];
  __shared__ __align__(16) short Bs[64 * 40];
  const int t = threadIdx.x;
  const int n0 = blockIdx.x << 6, m0 = blockIdx.y << 6;
  const int wv = t >> 6, l16 = t & 15, quad = (t & 63) >> 4;
  const int row = t >> 2, koff = (t & 3) << 3;

  auto loadA = [&](int k0) -> bf16x8 {
    if (Af) {
      const float* src = &Af[(size_t)(m0 + row) * 256 + k0 + koff];
      float4 f0 = *(const float4*)src;
      float4 f1 = *(const float4*)(src + 4);
      union { unsigned u[4]; bf16x8 v; } c;
      c.u[0] = pk2bf(f0.x, f0.y); c.u[1] = pk2bf(f0.z, f0.w);
      c.u[2] = pk2bf(f1.x, f1.y); c.u[3] = pk2bf(f1.z, f1.w);
      return c.v;
    }
    return *(const bf16x8*)&Ab[(size_t)(m0 + row) * 256 + k0 + koff];
  };

  f32x4 acc[4] = {};
  bf16x8 av = loadA(0);
  bf16x8 bv = *(const bf16x8*)&Bt[(size_t)(n0 + row) * 256 + koff];
  for (int k0 = 0; k0 < 256; k0 += 32) {
    __syncthreads();  // prior-iter frag reads done before overwrite
    *(bf16x8*)&As[row * 40 + koff] = av;
    *(bf16x8*)&Bs[row * 40 + koff] = bv;
    __syncthreads();
    if (k0 + 32 < 256) {  // prefetch next chunk before MFMA section
      av = loadA(k0 + 32);
      bv = *(const bf16x8*)&Bt[(size_t)(n0 + row) * 256 + k0 + 32 + koff];
    }
    bf16x8 a = *(const bf16x8*)&As[((wv << 4) + l16) * 40 + (quad << 3)];
#pragma unroll
    for (int jt = 0; jt < 4; jt++) {
      bf16x8 bb = *(const bf16x8*)&Bs[((jt << 4) + l16) * 40 + (quad << 3)];
      acc[jt] = __builtin_amdgcn_mfma_f32_16x16x32_bf16(a, bb, acc[jt], 0, 0, 0);
    }
  }
#pragma unroll
  for (int jt = 0; jt < 4; jt++) {
#pragma unroll
    for (int r = 0; r < 4; r++) {
      int mrow = m0 + (wv << 4) + (quad << 2) + r;
      int ncol = n0 + (jt << 4) + l16;
      float v = acc[jt][r];
      if (bias) v += bias[ncol];
      if (Cf) Cf[(size_t)mrow * N + ncol] = v;
      else    Cb[(size_t)mrow * N + ncol] = f2bf(v);
    }
  }
}

// ---------------------------------------------------------------------------
// Fused: conv5x5 depthwise + LN(128) + GELU + @Woff + tanh -> pos, then
// grid_sample of this pixel's group channels -> xs (bf16). Wave per (b,g,pix).
// Branch-free taps (clamp + weight*mask); weights preloaded to registers.
// ---------------------------------------------------------------------------
__global__ __launch_bounds__(256) void conv_pos_sample_kernel(
    const float* __restrict__ q, const float* __restrict__ conv_w,
    const float* __restrict__ conv_b, const float* __restrict__ ln_g,
    const float* __restrict__ ln_b, const float* __restrict__ Woff,
    float* __restrict__ pos, short* __restrict__ xsb)
{
  const int p = (blockIdx.x << 2) + (threadIdx.x >> 6);
  const int lane = threadIdx.x & 63;
  const int bg = p >> 10, pix = p & 1023;
  const int hh = pix >> 5, ww = pix & 31;
  const int b = bg >> 1, g = bg & 1;
  const int c0 = lane << 1;
  const float* qbase = q + ((size_t)(b << 10) << 8) + (g << 7) + c0;

  float wr0[25], wr1[25];
  {
    const float* w0 = conv_w + c0 * 25;
#pragma unroll
    for (int i = 0; i < 25; i++) { wr0[i] = w0[i]; wr1[i] = w0[i + 25]; }
  }

  float2 cb = *(const float2*)&conv_b[c0];
  float a0 = cb.x, a1 = cb.y;
#pragma unroll
  for (int dy = 0; dy < 5; dy++) {
    int y = hh + dy - 2;
    int yc = y < 0 ? 0 : (y > 31 ? 31 : y);
    float my = ((unsigned)y < 32u) ? 1.f : 0.f;
#pragma unroll
    for (int dx = 0; dx < 5; dx++) {
      int x = ww + dx - 2;
      int xc = x < 0 ? 0 : (x > 31 ? 31 : x);
      float m = ((unsigned)x < 32u) ? my : 0.f;
      float2 qv = *(const float2*)&qbase[(size_t)((yc << 5) + xc) << 8];
      a0 = fmaf(qv.x * m, wr0[dy * 5 + dx], a0);
      a1 = fmaf(qv.y * m, wr1[dy * 5 + dx], a1);
    }
  }
  float s1 = a0 + a1, s2 = a0 * a0 + a1 * a1;
#pragma unroll
  for (int o = 32; o; o >>= 1) { s1 += __shfl_xor(s1, o); s2 += __shfl_xor(s2, o); }
  float mu = s1 * (1.f / 128.f);
  float inv = rsqrtf(fmaf(-mu, mu, s2 * (1.f / 128.f)) + EPS_);
  float2 lg = *(const float2*)&ln_g[c0];
  float2 lb = *(const float2*)&ln_b[c0];
  float v0 = (a0 - mu) * inv * lg.x + lb.x;
  float v1 = (a1 - mu) * inv * lg.y + lb.y;
  float ge0 = 0.5f * v0 * (1.f + erff(v0 * 0.70710678118654752f));
  float ge1 = 0.5f * v1 * (1.f + erff(v1 * 0.70710678118654752f));
  float2 W0 = *(const float2*)&Woff[c0 * 2];
  float2 W1 = *(const float2*)&Woff[c0 * 2 + 2];
  float o0 = ge0 * W0.x + ge1 * W1.x;
  float o1 = ge0 * W0.y + ge1 * W1.y;
#pragma unroll
  for (int o = 32; o; o >>= 1) { o0 += __shfl_xor(o0, o); o1 += __shfl_xor(o1, o); }
  float py = tanhf(o0) * 0.0625f + ((hh + 0.5f) * 0.0625f - 1.f);
  float px = tanhf(o1) * 0.0625f + ((ww + 0.5f) * 0.0625f - 1.f);
  if (lane == 0)
    ((float2*)pos)[(bg << 10) + pix] = make_float2(py, px);

  float x = (px + 1.f) * 15.5f;
  float y = (py + 1.f) * 15.5f;
  float x0f = floorf(x), y0f = floorf(y);
  int ix0 = (int)x0f, iy0 = (int)y0f;
  float fx = x - x0f, fy = y - y0f;
  float ac0 = 0.f, ac1 = 0.f;
#pragma unroll
  for (int dy = 0; dy < 2; dy++) {
#pragma unroll
    for (int dx = 0; dx < 2; dx++) {
      int yi = iy0 + dy, xi = ix0 + dx;
      int yc = yi < 0 ? 0 : (yi > 31 ? 31 : yi);
      int xc = xi < 0 ? 0 : (xi > 31 ? 31 : xi);
      float valid = ((unsigned)yi < 32u && (unsigned)xi < 32u) ? 1.f : 0.f;
      float w = (dy ? fy : 1.f - fy) * (dx ? fx : 1.f - fx) * valid;
      float2 qv = *(const float2*)&qbase[(size_t)((yc << 5) + xc) << 8];
      ac0 = fmaf(w, qv.x, ac0);
      ac1 = fmaf(w, qv.y, ac1);
    }
  }
  *(unsigned*)&xsb[(size_t)((b << 10) + pix) * 256 + (g << 7) + c0] = pk2bf(ac0, ac1);
}

// ---------------------------------------------------------------------------
// Fused attention v15 = v13c body (cooperative V-stage + barriers, pinned
// V/pos prefetch) + pinned K PREFETCH + XCD-aware block swizzle.
// 1D grid 1024: lid = c + 8*hbl + 64*it  (XCD = lid%8 under round-robin) ->
// all 16 it-blocks of one (h,b) land on one XCD; its ~200 KB K/V/q/pos
// working set stays L2-resident instead of thrashing across 8 XCDs.
// ---------------------------------------------------------------------------
__global__ __launch_bounds__(256, 4) void attn_kernel(
    const float* __restrict__ q, const short* __restrict__ kvb,
    const float* __restrict__ pos, const unsigned* __restrict__ rpeq,
    short* __restrict__ ao)
{
  // ---- XCD swizzle decode: lid = c + 8*hbl + 64*it (bijective on [0,1024))
  const int lid = blockIdx.x;
  const int it  = lid >> 6;
  const int hb  = ((lid & 7) << 3) + ((lid >> 3) & 7);
  const int h = hb & 7, b = hb >> 3;
  const int g = h >> 2, t = threadIdx.x;
  const int wv = t >> 6, l16 = t & 15, quad = (t & 63) >> 4;

  __shared__ __align__(16) short PL[64 * 72];     // P (wave-local rows)
  __shared__ __align__(16) short Vt[32 * 68];     // V^T [d][j]
  __shared__ float2 posT[64];                     // (-15.5*py, -15.5*px)
  __shared__ __align__(16) unsigned rpe8[64 * 64];  // fp8 quad per point

  // ---- stage fp8 rpe quad table: coalesced copy from prebuilt rpeq
  {
    const unsigned* src = rpeq + (h << 12);
    for (int i = t; i < 4096; i += 256) rpe8[i] = src[i];
  }

  // ---- Q A-frag from global (once), scaled by ASCALE*LOG2E
  const int row0 = (it << 6) + (wv << 4);
  bf16x8 aq;
  {
    const float* src = q + (size_t)((b << 10) + row0 + l16) * 256 + (h << 5) + (quad << 3);
    float4 f0 = *(const float4*)src;
    float4 f1 = *(const float4*)(src + 4);
    const float sc = ASCALE * LOG2E;
    union { unsigned u[4]; bf16x8 v; } c;
    c.u[0] = pk2bf(f0.x * sc, f0.y * sc); c.u[1] = pk2bf(f0.z * sc, f0.w * sc);
    c.u[2] = pk2bf(f1.x * sc, f1.y * sc); c.u[3] = pk2bf(f1.z * sc, f1.w * sc);
    aq = c.v;
  }

  // sampling coords (origin +31): wave's 16 rows share one raster row
  const float ayc = 15.5f * (((row0 >> 5) + 0.5f) * 0.0625f - 1.f) + 31.f;
  float ax[4];
#pragma unroll
  for (int r = 0; r < 4; r++) {
    int ix = (row0 & 31) + (quad << 2) + r;
    ax[r] = 15.5f * ((ix + 0.5f) * 0.0625f - 1.f) + 31.f;
  }

  bf16x8 vones;
#pragma unroll
  for (int i = 0; i < 8; i++) vones[i] = (short)0x3F80;  // bf16 1.0

  // ---- strength-reduced pointer bases (advance by constants per kt)
  const int vj = t & 63, vc = t >> 6;
  const short* vsrc = kvb + (size_t)((b << 10) + vj) * 512 + 256 + (h << 5) + (vc << 3);
  const short* ksrc = kvb + (size_t)((b << 10) + l16) * 512 + (h << 5) + (quad << 3);
  const float2* psrc = (const float2*)pos + (((b << 1) + g) << 10) + t;

  f32x4 Oacc[2] = {};
  f32x4 lacc = {};

  // ---- prefetch kt=0's V row, pos, and 4 K frags into registers
  bf16x8 vv_cur = *(const bf16x8*)vsrc;
  vsrc += 32768;
  float2 pp_cur = make_float2(0.f, 0.f);
  if (t < 64) pp_cur = *psrc;
  psrc += 64;
  bf16x8 kf_cur[4];
#pragma unroll
  for (int jt = 0; jt < 4; jt++)
    kf_cur[jt] = *(const bf16x8*)(ksrc + (size_t)jt * 8192);
  ksrc += 32768;

  for (int kt = 0; kt < 16; kt++) {
    __syncthreads();  // [b1] prior PV reads done (covers rpe8 copy at kt=0)
    // ---- stage V^T from the prefetched registers (pure ds_write)
#pragma unroll
    for (int k2 = 0; k2 < 8; k2++) Vt[((vc << 3) + k2) * 68 + vj] = vv_cur[k2];
    if (t < 64)
      posT[t] = make_float2(-15.5f * pp_cur.x, -15.5f * pp_cur.y);
    __syncthreads();  // [b2]

    // ---- issue NEXT kt's V/pos/K loads (complete under this kt's compute)
    bf16x8 vv_nxt = vv_cur;
    float2 pp_nxt = pp_cur;
    bf16x8 kf_nxt[4];
#pragma unroll
    for (int jt = 0; jt < 4; jt++) kf_nxt[jt] = kf_cur[jt];
    if (kt < 15) {
      vv_nxt = *(const bf16x8*)vsrc;
      if (t < 64) pp_nxt = *psrc;
#pragma unroll
      for (int jt = 0; jt < 4; jt++)
        kf_nxt[jt] = *(const bf16x8*)(ksrc + (size_t)jt * 8192);
    }
    vsrc += 32768; psrc += 64; ksrc += 32768;

    // ---- QK^T: 4 MFMA on the prefetched K frags (no load wait)
    f32x4 S[4];
#pragma unroll
    for (int jt = 0; jt < 4; jt++) {
      f32x4 z = {};
      S[jt] = __builtin_amdgcn_mfma_f32_16x16x32_bf16(aq, kf_cur[jt], z, 0, 0, 0);
    }

    // ---- y-chains for the 4 j's (posT broadcast reads), hoisted
    float fyv[4];
    int ybv[4];
    float wyv[4];
#pragma unroll
    for (int jt = 0; jt < 4; jt++) {
      float2 bv = posT[(jt << 4) + l16];
      float ys = ayc + bv.x;
      float y0f = floorf(ys);
      fyv[jt] = ys - y0f;
      ybv[jt] = (int)y0f << 6;
      wyv[jt] = bv.y;
    }

    // ---- bias sample + p = exp2(S+bias), per jt (v12-exact fmaf lerp)
    unsigned pu[4][2];
#pragma unroll
    for (int jt = 0; jt < 4; jt++) {
      float fy = fyv[jt];
      int ybase = ybv[jt];
      float pv[4];
#pragma unroll
      for (int r = 0; r < 4; r++) {
        float sx = ax[r] + wyv[jt];
        float x0f = floorf(sx);
        float fx = sx - x0f;
        unsigned u = rpe8[ybase + (int)x0f];
        float g00, g10, g01, g11;
        unpack_fp8_quad(u, g00, g10, g01, g11);
        float h0 = fmaf(fx, g01 - g00, g00);
        float h1 = fmaf(fx, g11 - g10, g10);
        float bias = fmaf(fy, h1 - h0, h0);
        pv[r] = exp2_fast(S[jt][r] + bias);
      }
      pu[jt][0] = pk2bf(pv[0], pv[1]);
      pu[jt][1] = pk2bf(pv[2], pv[3]);
    }

    // ---- wave-local P write -> A-frag read -> PV + l (no barrier)
#pragma unroll
    for (int jt = 0; jt < 4; jt++) {
      int cb = (jt << 4) + l16;
      int rb = ((wv << 4) + (quad << 2)) * 72 + cb;
      PL[rb]       = (short)(pu[jt][0] & 0xffff);
      PL[rb + 72]  = (short)(pu[jt][0] >> 16);
      PL[rb + 144] = (short)(pu[jt][1] & 0xffff);
      PL[rb + 216] = (short)(pu[jt][1] >> 16);
    }
    bf16x8 pa0 = *(const bf16x8*)&PL[((wv << 4) + l16) * 72 + (quad << 3)];
    bf16x8 pa1 = *(const bf16x8*)&PL[((wv << 4) + l16) * 72 + 32 + (quad << 3)];
#pragma unroll
    for (int dt = 0; dt < 2; dt++) {
      bf16x8 vb0 = *(const bf16x8*)&Vt[((dt << 4) + l16) * 68 + (quad << 3)];
      bf16x8 vb1 = *(const bf16x8*)&Vt[((dt << 4) + l16) * 68 + 32 + (quad << 3)];
      Oacc[dt] = __builtin_amdgcn_mfma_f32_16x16x32_bf16(pa0, vb0, Oacc[dt], 0, 0, 0);
      Oacc[dt] = __builtin_amdgcn_mfma_f32_16x16x32_bf16(pa1, vb1, Oacc[dt], 0, 0, 0);
    }
    lacc = __builtin_amdgcn_mfma_f32_16x16x32_bf16(pa0, vones, lacc, 0, 0, 0);
    lacc = __builtin_amdgcn_mfma_f32_16x16x32_bf16(pa1, vones, lacc, 0, 0, 0);

    // ---- pin the prefetched V/pos/K (issued above; latency hid here)
    if (kt < 15) {
      uint4 p4 = __builtin_bit_cast(uint4, vv_nxt);
      uint4 k0 = __builtin_bit_cast(uint4, kf_nxt[0]);
      uint4 k1 = __builtin_bit_cast(uint4, kf_nxt[1]);
      uint4 k2 = __builtin_bit_cast(uint4, kf_nxt[2]);
      uint4 k3 = __builtin_bit_cast(uint4, kf_nxt[3]);
      asm volatile("" :: "v"(p4.x), "v"(p4.y), "v"(p4.z), "v"(p4.w),
                         "v"(pp_nxt.x), "v"(pp_nxt.y),
                         "v"(k0.x), "v"(k0.y), "v"(k0.z), "v"(k0.w),
                         "v"(k1.x), "v"(k1.y), "v"(k1.z), "v"(k1.w),
                         "v"(k2.x), "v"(k2.y), "v"(k2.z), "v"(k2.w),
                         "v"(k3.x), "v"(k3.y), "v"(k3.z), "v"(k3.w));
    }
    vv_cur = vv_nxt;
    pp_cur = pp_nxt;
#pragma unroll
    for (int jt = 0; jt < 4; jt++) kf_cur[jt] = kf_nxt[jt];
  }

  // ---- epilogue -> ao bf16
#pragma unroll
  for (int r = 0; r < 4; r++) {
    float inv = 1.f / lacc[r];
    int row = row0 + (quad << 2) + r;
#pragma unroll
    for (int dt = 0; dt < 2; dt++) {
      ao[(size_t)((b << 10) + row) * 256 + (h << 5) + (dt << 4) + l16] =
          f2bf(Oacc[dt][r] * inv);
    }
  }
}

// ---------------------------------------------------------------------------
extern "C" void kernel_launch(void* const* d_in, const int* in_sizes, int n_in,
                              void* d_out, int out_size, void* d_ws, size_t ws_size,
                              hipStream_t stream) {
  (void)in_sizes; (void)n_in; (void)out_size; (void)ws_size;
  const float* x      = (const float*)d_in[0];
  const float* Wq     = (const float*)d_in[1];
  const float* Wkv    = (const float*)d_in[2];
  const float* conv_w = (const float*)d_in[3];
  const float* conv_b = (const float*)d_in[4];
  const float* ln_g   = (const float*)d_in[5];
  const float* ln_b   = (const float*)d_in[6];
  const float* Woff   = (const float*)d_in[7];
  const float* rpe    = (const float*)d_in[8];
  const float* Wout   = (const float*)d_in[9];
  const float* bout   = (const float*)d_in[10];
  float* out = (float*)d_out;

  float* ws      = (float*)d_ws;
  float* q       = ws;                        // [0 .. 2097152)
  float* pos     = ws + 2097152;              // [.. 2129920)
  short* kvb     = (short*)(ws + 2129920);    // 8192*512 bf16 = 2,097,152 f32 [.. 4227072)
  short* xsb     = (short*)(ws + 4227072);    // 8192*256 bf16 = 1,048,576 f32 [.. 5275648)
  short* aob     = (short*)(ws + 5275648);    // 8192*256 bf16 = 1,048,576 f32 [.. 6324224)
  short* Wkvt    = (short*)(ws + 6324224);    // 512*256 bf16  =    65,536 f32 [.. 6389760)
  short* Woutt   = (short*)(ws + 6389760);    // 256*256 bf16  =    32,768 f32 [.. 6422528)
  short* Wqt     = (short*)(ws + 6422528);    // 256*256 bf16  =    32,768 f32 [.. 6455296)
  unsigned* rpeq = (unsigned*)(ws + 6455296); // 8*4096 u32    =    32,768 f32 [.. 6488064)
  // total 6,488,064 f32 = 26.0 MB

  // 0. weight transposes + global fp8 rpe quad table (merged)
  prep_all<<<1152, 256, 0, stream>>>(Wkv, Wout, Wq, rpe, Wkvt, Woutt, Wqt, rpeq);
  // 1. q = x @ Wq (bf16 MFMA, f32 A staged+converted, f32 out)
  gemm_bf16<<<dim3(4, 128), 256, 0, stream>>>(nullptr, x, Wqt, q, nullptr, nullptr, 256);
  // 2+3. conv + LN + GELU + Woff + tanh -> pos, fused grid_sample -> xs
  conv_pos_sample_kernel<<<4096, 256, 0, stream>>>(q, conv_w, conv_b, ln_g, ln_b,
                                                   Woff, pos, xsb);
  // 4. kv = xs @ Wkv (bf16 MFMA, bf16 out, interleaved K|V rows)
  gemm_bf16<<<dim3(8, 128), 256, 0, stream>>>(xsb, nullptr, Wkvt, nullptr, kvb, nullptr, 512);
  // 5. fused attention v15 (K prefetch + XCD swizzle) -> ao (bf16)
  attn_kernel<<<1024, 256, 0, stream>>>(q, kvb, pos, rpeq, aob);
  // 6. out = ao @ Wout + bout (bf16 MFMA, f32 out)
  gemm_bf16<<<dim3(4, 128), 256, 0, stream>>>(aob, nullptr, Woutt, out, nullptr, bout, 256);
}

// Round 19
// 187.081 us; speedup vs baseline: 1.1045x; 1.0179x over previous
//
#include <hip/hip_runtime.h>
#include <hip/hip_bf16.h>
#include <hip/hip_fp16.h>
#include <hip/hip_fp8.h>

// DeformableAttention on MI355X.
// prep_all(weights^T bf16 + global fp8 rpe quad table) -> gemm_bf16(q) ->
// fused conv+LN+GELU+pos+sample (branch-free taps) -> gemm_bf16(kv) ->
// fused flash-attn v16 (= v13c body: pinned V/pos prefetch, direct K loads
// + XCD-aware block swizzle ONLY; v15's K-prefetch dropped as the suspected
// +2us regression) -> gemm_bf16(out,+bias)

#define EPS_ 1e-5f
#define ASCALE 0.17677669529663687f      // 1/sqrt(32)
#define LOG2E  1.4426950408889634f

typedef __attribute__((ext_vector_type(8))) short bf16x8;
typedef __attribute__((ext_vector_type(4))) float f32x4;

__device__ __forceinline__ short f2bf(float f) {
  union { float f; unsigned u; } v; v.f = f;
  unsigned r = (v.u + 0x7fffu + ((v.u >> 16) & 1u)) >> 16;  // RNE
  return (short)r;
}
__device__ __forceinline__ unsigned pk2bf(float a, float b) {
  union { __hip_bfloat162 h; unsigned u; } v;
  v.h = __float22bfloat162_rn(make_float2(a, b));
  return v.u;
}
__device__ __forceinline__ float exp2_fast(float x) {
  return __builtin_amdgcn_exp2f(x);
}

// fp8 e4m3 quad pack/unpack: HW v_cvt_pk_* on gfx950, sw fallback otherwise.
__device__ __forceinline__ unsigned pack_fp8_quad(float v00, float v10,
                                                  float v01, float v11) {
#if __has_builtin(__builtin_amdgcn_cvt_pk_fp8_f32)
  int r = 0;
  r = __builtin_amdgcn_cvt_pk_fp8_f32(v00, v10, r, false);  // bytes 0,1
  r = __builtin_amdgcn_cvt_pk_fp8_f32(v01, v11, r, true);   // bytes 2,3
  return (unsigned)r;
#else
  __hip_fp8x2_e4m3 elo(make_float2(v00, v10));
  __hip_fp8x2_e4m3 ehi(make_float2(v01, v11));
  return (unsigned)(unsigned short)elo.__x |
         ((unsigned)(unsigned short)ehi.__x << 16);
#endif
}
__device__ __forceinline__ void unpack_fp8_quad(unsigned u, float& g00,
                                                float& g10, float& g01,
                                                float& g11) {
#if __has_builtin(__builtin_amdgcn_cvt_pk_f32_fp8)
  auto ga = __builtin_amdgcn_cvt_pk_f32_fp8((int)u, false);  // (v00, v10)
  auto gb = __builtin_amdgcn_cvt_pk_f32_fp8((int)u, true);   // (v01, v11)
  g00 = ga[0]; g10 = ga[1]; g01 = gb[0]; g11 = gb[1];
#else
  __hip_fp8x2_e4m3 plo, phi;
  plo.__x = (__hip_fp8x2_storage_t)(unsigned short)(u & 0xffffu);
  phi.__x = (__hip_fp8x2_storage_t)(unsigned short)(u >> 16);
  float2 fa = (float2)plo, fb = (float2)phi;
  g00 = fa.x; g10 = fa.y; g01 = fb.x; g11 = fb.y;
#endif
}

// ---------------------------------------------------------------------------
// Prep: bids [0,1024) weight transposes; bids [1024,1152) build the global
// fp8 rpe quad table (8 x 64 x 64 u32), once per head.
// ---------------------------------------------------------------------------
__global__ __launch_bounds__(256) void prep_all(
    const float* __restrict__ Wkv, const float* __restrict__ Wout,
    const float* __restrict__ Wq, const float* __restrict__ rpe,
    short* __restrict__ Wkvt, short* __restrict__ Woutt,
    short* __restrict__ Wqt, unsigned* __restrict__ rpeq)
{
  int bid = blockIdx.x, k = threadIdx.x;
  if (bid >= 1024) {
    int i = (bid - 1024) * 256 + k;   // 0..32767
    int h = i >> 12, idx = i & 4095;
    int ty = idx >> 6, tx = idx & 63;
    const float* rp = rpe + h * 3969;
    float v00 = 0.f, v10 = 0.f, v01 = 0.f, v11 = 0.f;
    if (tx <= 62) {
      if (ty <= 62) v00 = rp[ty * 63 + tx] * LOG2E;
      if (ty <= 61) v10 = rp[(ty + 1) * 63 + tx] * LOG2E;
    }
    if (tx <= 61) {
      if (ty <= 62) v01 = rp[ty * 63 + tx + 1] * LOG2E;
      if (ty <= 61) v11 = rp[(ty + 1) * 63 + tx + 1] * LOG2E;
    }
    rpeq[i] = pack_fp8_quad(v00, v10, v01, v11);
    return;
  }
  if (bid < 512) Wkvt[bid * 256 + k] = f2bf(Wkv[k * 512 + bid]);
  else if (bid < 768) { int n = bid - 512; Woutt[n * 256 + k] = f2bf(Wout[k * 256 + n]); }
  else { int n = bid - 768; Wqt[n * 256 + k] = f2bf(Wq[k * 256 + n]); }
}

// ---------------------------------------------------------------------------
// bf16 MFMA GEMM: C[M,N] = A[M,256] @ Bt[N,256]^T (+bias), with prefetch.
// ---------------------------------------------------------------------------
__global__ __launch_bounds__(256) void gemm_bf16(
    const short* __restrict__ Ab, const float* __restrict__ Af,
    const short* __restrict__ Bt,
    float* __restrict__ Cf, short* __restrict__ Cb,
    const float* __restrict__ bias, int N)
{
  __shared__ __align__(16) short As[64 * 40];
  __shared__ __align__(16) short Bs[64 * 40];
  const int t = threadIdx.x;
  const int n0 = blockIdx.x << 6, m0 = blockIdx.y << 6;
  const int wv = t >> 6, l16 = t & 15, quad = (t & 63) >> 4;
  const int row = t >> 2, koff = (t & 3) << 3;

  auto loadA = [&](int k0) -> bf16x8 {
    if (Af) {
      const float* src = &Af[(size_t)(m0 + row) * 256 + k0 + koff];
      float4 f0 = *(const float4*)src;
      float4 f1 = *(const float4*)(src + 4);
      union { unsigned u[4]; bf16x8 v; } c;
      c.u[0] = pk2bf(f0.x, f0.y); c.u[1] = pk2bf(f0.z, f0.w);
      c.u[2] = pk2bf(f1.x, f1.y); c.u[3] = pk2bf(f1.z, f1.w);
      return c.v;
    }
    return *(const bf16x8*)&Ab[(size_t)(m0 + row) * 256 + k0 + koff];
  };

  f32x4 acc[4] = {};
  bf16x8 av = loadA(0);
  bf16x8 bv = *(const bf16x8*)&Bt[(size_t)(n0 + row) * 256 + koff];
  for (int k0 = 0; k0 < 256; k0 += 32) {
    __syncthreads();  // prior-iter frag reads done before overwrite
    *(bf16x8*)&As[row * 40 + koff] = av;
    *(bf16x8*)&Bs[row * 40 + koff] = bv;
    __syncthreads();
    if (k0 + 32 < 256) {  // prefetch next chunk before MFMA section
      av = loadA(k0 + 32);
      bv = *(const bf16x8*)&Bt[(size_t)(n0 + row) * 256 + k0 + 32 + koff];
    }
    bf16x8 a = *(const bf16x8*)&As[((wv << 4) + l16) * 40 + (quad << 3)];
#pragma unroll
    for (int jt = 0; jt < 4; jt++) {
      bf16x8 bb = *(const bf16x8*)&Bs[((jt << 4) + l16) * 40 + (quad << 3)];
      acc[jt] = __builtin_amdgcn_mfma_f32_16x16x32_bf16(a, bb, acc[jt], 0, 0, 0);
    }
  }
#pragma unroll
  for (int jt = 0; jt < 4; jt++) {
#pragma unroll
    for (int r = 0; r < 4; r++) {
      int mrow = m0 + (wv << 4) + (quad << 2) + r;
      int ncol = n0 + (jt << 4) + l16;
      float v = acc[jt][r];
      if (bias) v += bias[ncol];
      if (Cf) Cf[(size_t)mrow * N + ncol] = v;
      else    Cb[(size_t)mrow * N + ncol] = f2bf(v);
    }
  }
}

// ---------------------------------------------------------------------------
// Fused: conv5x5 depthwise + LN(128) + GELU + @Woff + tanh -> pos, then
// grid_sample of this pixel's group channels -> xs (bf16). Wave per (b,g,pix).
// Branch-free taps (clamp + weight*mask); weights preloaded to registers.
// ---------------------------------------------------------------------------
__global__ __launch_bounds__(256) void conv_pos_sample_kernel(
    const float* __restrict__ q, const float* __restrict__ conv_w,
    const float* __restrict__ conv_b, const float* __restrict__ ln_g,
    const float* __restrict__ ln_b, const float* __restrict__ Woff,
    float* __restrict__ pos, short* __restrict__ xsb)
{
  const int p = (blockIdx.x << 2) + (threadIdx.x >> 6);
  const int lane = threadIdx.x & 63;
  const int bg = p >> 10, pix = p & 1023;
  const int hh = pix >> 5, ww = pix & 31;
  const int b = bg >> 1, g = bg & 1;
  const int c0 = lane << 1;
  const float* qbase = q + ((size_t)(b << 10) << 8) + (g << 7) + c0;

  float wr0[25], wr1[25];
  {
    const float* w0 = conv_w + c0 * 25;
#pragma unroll
    for (int i = 0; i < 25; i++) { wr0[i] = w0[i]; wr1[i] = w0[i + 25]; }
  }

  float2 cb = *(const float2*)&conv_b[c0];
  float a0 = cb.x, a1 = cb.y;
#pragma unroll
  for (int dy = 0; dy < 5; dy++) {
    int y = hh + dy - 2;
    int yc = y < 0 ? 0 : (y > 31 ? 31 : y);
    float my = ((unsigned)y < 32u) ? 1.f : 0.f;
#pragma unroll
    for (int dx = 0; dx < 5; dx++) {
      int x = ww + dx - 2;
      int xc = x < 0 ? 0 : (x > 31 ? 31 : x);
      float m = ((unsigned)x < 32u) ? my : 0.f;
      float2 qv = *(const float2*)&qbase[(size_t)((yc << 5) + xc) << 8];
      a0 = fmaf(qv.x * m, wr0[dy * 5 + dx], a0);
      a1 = fmaf(qv.y * m, wr1[dy * 5 + dx], a1);
    }
  }
  float s1 = a0 + a1, s2 = a0 * a0 + a1 * a1;
#pragma unroll
  for (int o = 32; o; o >>= 1) { s1 += __shfl_xor(s1, o); s2 += __shfl_xor(s2, o); }
  float mu = s1 * (1.f / 128.f);
  float inv = rsqrtf(fmaf(-mu, mu, s2 * (1.f / 128.f)) + EPS_);
  float2 lg = *(const float2*)&ln_g[c0];
  float2 lb = *(const float2*)&ln_b[c0];
  float v0 = (a0 - mu) * inv * lg.x + lb.x;
  float v1 = (a1 - mu) * inv * lg.y + lb.y;
  float ge0 = 0.5f * v0 * (1.f + erff(v0 * 0.70710678118654752f));
  float ge1 = 0.5f * v1 * (1.f + erff(v1 * 0.70710678118654752f));
  float2 W0 = *(const float2*)&Woff[c0 * 2];
  float2 W1 = *(const float2*)&Woff[c0 * 2 + 2];
  float o0 = ge0 * W0.x + ge1 * W1.x;
  float o1 = ge0 * W0.y + ge1 * W1.y;
#pragma unroll
  for (int o = 32; o; o >>= 1) { o0 += __shfl_xor(o0, o); o1 += __shfl_xor(o1, o); }
  float py = tanhf(o0) * 0.0625f + ((hh + 0.5f) * 0.0625f - 1.f);
  float px = tanhf(o1) * 0.0625f + ((ww + 0.5f) * 0.0625f - 1.f);
  if (lane == 0)
    ((float2*)pos)[(bg << 10) + pix] = make_float2(py, px);

  float x = (px + 1.f) * 15.5f;
  float y = (py + 1.f) * 15.5f;
  float x0f = floorf(x), y0f = floorf(y);
  int ix0 = (int)x0f, iy0 = (int)y0f;
  float fx = x - x0f, fy = y - y0f;
  float ac0 = 0.f, ac1 = 0.f;
#pragma unroll
  for (int dy = 0; dy < 2; dy++) {
#pragma unroll
    for (int dx = 0; dx < 2; dx++) {
      int yi = iy0 + dy, xi = ix0 + dx;
      int yc = yi < 0 ? 0 : (yi > 31 ? 31 : yi);
      int xc = xi < 0 ? 0 : (xi > 31 ? 31 : xi);
      float valid = ((unsigned)yi < 32u && (unsigned)xi < 32u) ? 1.f : 0.f;
      float w = (dy ? fy : 1.f - fy) * (dx ? fx : 1.f - fx) * valid;
      float2 qv = *(const float2*)&qbase[(size_t)((yc << 5) + xc) << 8];
      ac0 = fmaf(w, qv.x, ac0);
      ac1 = fmaf(w, qv.y, ac1);
    }
  }
  *(unsigned*)&xsb[(size_t)((b << 10) + pix) * 256 + (g << 7) + c0] = pk2bf(ac0, ac1);
}

// ---------------------------------------------------------------------------
// Fused attention v16 = v13c body (pinned V/pos prefetch, direct K loads,
// ksrc advance) + XCD-aware block swizzle.  1D grid 1024:
// lid = c + 8*hbl + 64*it -> all 16 it-blocks of one (h,b) share lid%8 =
// one XCD; working set L2-resident (v15-proven: FETCH 37.9 -> 8.8 MB).
// ---------------------------------------------------------------------------
__global__ __launch_bounds__(256, 4) void attn_kernel(
    const float* __restrict__ q, const short* __restrict__ kvb,
    const float* __restrict__ pos, const unsigned* __restrict__ rpeq,
    short* __restrict__ ao)
{
  // ---- XCD swizzle decode (bijective on [0,1024))
  const int lid = blockIdx.x;
  const int it  = lid >> 6;
  const int hb  = ((lid & 7) << 3) + ((lid >> 3) & 7);
  const int h = hb & 7, b = hb >> 3;
  const int g = h >> 2, t = threadIdx.x;
  const int wv = t >> 6, l16 = t & 15, quad = (t & 63) >> 4;

  __shared__ __align__(16) short PL[64 * 72];     // P (wave-local rows)
  __shared__ __align__(16) short Vt[32 * 68];     // V^T [d][j]
  __shared__ float2 posT[64];                     // (-15.5*py, -15.5*px)
  __shared__ __align__(16) unsigned rpe8[64 * 64];  // fp8 quad per point

  // ---- stage fp8 rpe quad table: coalesced copy from prebuilt rpeq
  {
    const unsigned* src = rpeq + (h << 12);
    for (int i = t; i < 4096; i += 256) rpe8[i] = src[i];
  }

  // ---- Q A-frag from global (once), scaled by ASCALE*LOG2E
  const int row0 = (it << 6) + (wv << 4);
  bf16x8 aq;
  {
    const float* src = q + (size_t)((b << 10) + row0 + l16) * 256 + (h << 5) + (quad << 3);
    float4 f0 = *(const float4*)src;
    float4 f1 = *(const float4*)(src + 4);
    const float sc = ASCALE * LOG2E;
    union { unsigned u[4]; bf16x8 v; } c;
    c.u[0] = pk2bf(f0.x * sc, f0.y * sc); c.u[1] = pk2bf(f0.z * sc, f0.w * sc);
    c.u[2] = pk2bf(f1.x * sc, f1.y * sc); c.u[3] = pk2bf(f1.z * sc, f1.w * sc);
    aq = c.v;
  }

  // sampling coords (origin +31): wave's 16 rows share one raster row
  const float ayc = 15.5f * (((row0 >> 5) + 0.5f) * 0.0625f - 1.f) + 31.f;
  float ax[4];
#pragma unroll
  for (int r = 0; r < 4; r++) {
    int ix = (row0 & 31) + (quad << 2) + r;
    ax[r] = 15.5f * ((ix + 0.5f) * 0.0625f - 1.f) + 31.f;
  }

  bf16x8 vones;
#pragma unroll
  for (int i = 0; i < 8; i++) vones[i] = (short)0x3F80;  // bf16 1.0

  // ---- strength-reduced pointer bases (advance by constants per kt)
  const int vj = t & 63, vc = t >> 6;
  const short* vsrc = kvb + (size_t)((b << 10) + vj) * 512 + 256 + (h << 5) + (vc << 3);
  const short* ksrc = kvb + (size_t)((b << 10) + l16) * 512 + (h << 5) + (quad << 3);
  const float2* psrc = (const float2*)pos + (((b << 1) + g) << 10) + t;

  f32x4 Oacc[2] = {};
  f32x4 lacc = {};

  // ---- prefetch kt=0's V row + pos into registers
  bf16x8 vv_cur = *(const bf16x8*)vsrc;
  vsrc += 32768;
  float2 pp_cur = make_float2(0.f, 0.f);
  if (t < 64) pp_cur = *psrc;
  psrc += 64;

  for (int kt = 0; kt < 16; kt++) {
    __syncthreads();  // [b1] prior PV reads done (covers rpe8 copy at kt=0)
    // ---- stage V^T from the prefetched registers (pure ds_write now)
#pragma unroll
    for (int k2 = 0; k2 < 8; k2++) Vt[((vc << 3) + k2) * 68 + vj] = vv_cur[k2];
    if (t < 64)
      posT[t] = make_float2(-15.5f * pp_cur.x, -15.5f * pp_cur.y);
    __syncthreads();  // [b2]

    // ---- issue NEXT kt's V/pos loads (complete under this kt's compute)
    bf16x8 vv_nxt = vv_cur;
    float2 pp_nxt = pp_cur;
    if (kt < 15) {
      vv_nxt = *(const bf16x8*)vsrc;
      if (t < 64) pp_nxt = *psrc;
    }
    vsrc += 32768; psrc += 64;

    // ---- QK^T first: 4 K B-frags from global (L2-hot) + 4 MFMA
    f32x4 S[4];
#pragma unroll
    for (int jt = 0; jt < 4; jt++) {
      bf16x8 bk = *(const bf16x8*)(ksrc + (size_t)jt * 8192);
      f32x4 z = {};
      S[jt] = __builtin_amdgcn_mfma_f32_16x16x32_bf16(aq, bk, z, 0, 0, 0);
    }

    // ---- y-chains for the 4 j's (posT broadcast reads), hoisted
    float fyv[4];
    int ybv[4];
    float wyv[4];
#pragma unroll
    for (int jt = 0; jt < 4; jt++) {
      float2 bv = posT[(jt << 4) + l16];
      float ys = ayc + bv.x;
      float y0f = floorf(ys);
      fyv[jt] = ys - y0f;
      ybv[jt] = (int)y0f << 6;
      wyv[jt] = bv.y;
    }

    // ---- bias sample + p = exp2(S+bias), per jt (v12-exact fmaf lerp)
    unsigned pu[4][2];
#pragma unroll
    for (int jt = 0; jt < 4; jt++) {
      float fy = fyv[jt];
      int ybase = ybv[jt];
      float pv[4];
#pragma unroll
      for (int r = 0; r < 4; r++) {
        float sx = ax[r] + wyv[jt];
        float x0f = floorf(sx);
        float fx = sx - x0f;
        unsigned u = rpe8[ybase + (int)x0f];
        float g00, g10, g01, g11;
        unpack_fp8_quad(u, g00, g10, g01, g11);
        float h0 = fmaf(fx, g01 - g00, g00);
        float h1 = fmaf(fx, g11 - g10, g10);
        float bias = fmaf(fy, h1 - h0, h0);
        pv[r] = exp2_fast(S[jt][r] + bias);
      }
      pu[jt][0] = pk2bf(pv[0], pv[1]);
      pu[jt][1] = pk2bf(pv[2], pv[3]);
    }

    // ---- wave-local P write -> A-frag read -> PV + l (no barrier)
#pragma unroll
    for (int jt = 0; jt < 4; jt++) {
      int cb = (jt << 4) + l16;
      int rb = ((wv << 4) + (quad << 2)) * 72 + cb;
      PL[rb]       = (short)(pu[jt][0] & 0xffff);
      PL[rb + 72]  = (short)(pu[jt][0] >> 16);
      PL[rb + 144] = (short)(pu[jt][1] & 0xffff);
      PL[rb + 216] = (short)(pu[jt][1] >> 16);
    }
    bf16x8 pa0 = *(const bf16x8*)&PL[((wv << 4) + l16) * 72 + (quad << 3)];
    bf16x8 pa1 = *(const bf16x8*)&PL[((wv << 4) + l16) * 72 + 32 + (quad << 3)];
#pragma unroll
    for (int dt = 0; dt < 2; dt++) {
      bf16x8 vb0 = *(const bf16x8*)&Vt[((dt << 4) + l16) * 68 + (quad << 3)];
      bf16x8 vb1 = *(const bf16x8*)&Vt[((dt << 4) + l16) * 68 + 32 + (quad << 3)];
      Oacc[dt] = __builtin_amdgcn_mfma_f32_16x16x32_bf16(pa0, vb0, Oacc[dt], 0, 0, 0);
      Oacc[dt] = __builtin_amdgcn_mfma_f32_16x16x32_bf16(pa1, vb1, Oacc[dt], 0, 0, 0);
    }
    lacc = __builtin_amdgcn_mfma_f32_16x16x32_bf16(pa0, vones, lacc, 0, 0, 0);
    lacc = __builtin_amdgcn_mfma_f32_16x16x32_bf16(pa1, vones, lacc, 0, 0, 0);

    // ---- pin the prefetched V/pos (issued above; latency hid here)
    if (kt < 15) {
      uint4 p4 = __builtin_bit_cast(uint4, vv_nxt);
      asm volatile("" :: "v"(p4.x), "v"(p4.y), "v"(p4.z), "v"(p4.w),
                         "v"(pp_nxt.x), "v"(pp_nxt.y));
    }
    vv_cur = vv_nxt;
    pp_cur = pp_nxt;
    ksrc += 32768;   // advance K base to the next 64-row tile
  }

  // ---- epilogue -> ao bf16
#pragma unroll
  for (int r = 0; r < 4; r++) {
    float inv = 1.f / lacc[r];
    int row = row0 + (quad << 2) + r;
#pragma unroll
    for (int dt = 0; dt < 2; dt++) {
      ao[(size_t)((b << 10) + row) * 256 + (h << 5) + (dt << 4) + l16] =
          f2bf(Oacc[dt][r] * inv);
    }
  }
}

// ---------------------------------------------------------------------------
extern "C" void kernel_launch(void* const* d_in, const int* in_sizes, int n_in,
                              void* d_out, int out_size, void* d_ws, size_t ws_size,
                              hipStream_t stream) {
  (void)in_sizes; (void)n_in; (void)out_size; (void)ws_size;
  const float* x      = (const float*)d_in[0];
  const float* Wq     = (const float*)d_in[1];
  const float* Wkv    = (const float*)d_in[2];
  const float* conv_w = (const float*)d_in[3];
  const float* conv_b = (const float*)d_in[4];
  const float* ln_g   = (const float*)d_in[5];
  const float* ln_b   = (const float*)d_in[6];
  const float* Woff   = (const float*)d_in[7];
  const float* rpe    = (const float*)d_in[8];
  const float* Wout   = (const float*)d_in[9];
  const float* bout   = (const float*)d_in[10];
  float* out = (float*)d_out;

  float* ws      = (float*)d_ws;
  float* q       = ws;                        // [0 .. 2097152)
  float* pos     = ws + 2097152;              // [.. 2129920)
  short* kvb     = (short*)(ws + 2129920);    // 8192*512 bf16 = 2,097,152 f32 [.. 4227072)
  short* xsb     = (short*)(ws + 4227072);    // 8192*256 bf16 = 1,048,576 f32 [.. 5275648)
  short* aob     = (short*)(ws + 5275648);    // 8192*256 bf16 = 1,048,576 f32 [.. 6324224)
  short* Wkvt    = (short*)(ws + 6324224);    // 512*256 bf16  =    65,536 f32 [.. 6389760)
  short* Woutt   = (short*)(ws + 6389760);    // 256*256 bf16  =    32,768 f32 [.. 6422528)
  short* Wqt     = (short*)(ws + 6422528);    // 256*256 bf16  =    32,768 f32 [.. 6455296)
  unsigned* rpeq = (unsigned*)(ws + 6455296); // 8*4096 u32    =    32,768 f32 [.. 6488064)
  // total 6,488,064 f32 = 26.0 MB

  // 0. weight transposes + global fp8 rpe quad table (merged)
  prep_all<<<1152, 256, 0, stream>>>(Wkv, Wout, Wq, rpe, Wkvt, Woutt, Wqt, rpeq);
  // 1. q = x @ Wq (bf16 MFMA, f32 A staged+converted, f32 out)
  gemm_bf16<<<dim3(4, 128), 256, 0, stream>>>(nullptr, x, Wqt, q, nullptr, nullptr, 256);
  // 2+3. conv + LN + GELU + Woff + tanh -> pos, fused grid_sample -> xs
  conv_pos_sample_kernel<<<4096, 256, 0, stream>>>(q, conv_w, conv_b, ln_g, ln_b,
                                                   Woff, pos, xsb);
  // 4. kv = xs @ Wkv (bf16 MFMA, bf16 out, interleaved K|V rows)
  gemm_bf16<<<dim3(8, 128), 256, 0, stream>>>(xsb, nullptr, Wkvt, nullptr, kvb, nullptr, 512);
  // 5. fused attention v16 (v13c body + XCD swizzle) -> ao (bf16)
  attn_kernel<<<1024, 256, 0, stream>>>(q, kvb, pos, rpeq, aob);
  // 6. out = ao @ Wout + bout (bf16 MFMA, f32 out)
  gemm_bf16<<<dim3(4, 128), 256, 0, stream>>>(aob, nullptr, Woutt, out, nullptr, bout, 256);
}